// Round 11
// baseline (539.688 us; speedup 1.0000x reference)
//
#include <hip/hip_runtime.h>
#include <math.h>

#define NNODES 65536
#define NEDGES 1048576
#define NF 32
#define EF 16
#define HD 128
#define NACT 10
#define NB 64
#define NPER 1024

typedef unsigned short u16;
typedef float  vf2  __attribute__((ext_vector_type(2)));
typedef float  vf4  __attribute__((ext_vector_type(4)));
typedef __bf16 vbf8 __attribute__((ext_vector_type(8)));
#define BC8(v) __builtin_bit_cast(vbf8, v)
#define WB() __builtin_amdgcn_wave_barrier()   // compile-time phase fence, no HW cost

__device__ __forceinline__ float leakyf(float v) { return v > 0.0f ? v : 0.01f * v; }
__device__ __forceinline__ vf2 fma2(vf2 a, vf2 b, vf2 c) { return __builtin_elementwise_fma(a, b, c); }
__device__ __forceinline__ vf2 max2(vf2 a, vf2 b) { return __builtin_elementwise_max(a, b); }
__device__ __forceinline__ vf2 splat2(float s) { vf2 r = {s, s}; return r; }

__device__ __forceinline__ u16 f2bf(float x) {
    unsigned u = __float_as_uint(x);
    return (u16)((u + 0x7FFFu + ((u >> 16) & 1u)) >> 16);
}
__device__ __forceinline__ float bf2f(u16 h) { return __uint_as_float(((unsigned)h) << 16); }

// unpack one dword of 2 packed bf16 (features 2i [low], 2i+1 [high]) to vf2
__device__ __forceinline__ vf2 up2(unsigned d) {
    vf2 r = { __uint_as_float(d << 16), __uint_as_float(d & 0xFFFF0000u) };
    return r;
}

// split f32x4 into bf16-hi and bf16-lo packed pairs (hi + lo ~= full f32 precision)
__device__ __forceinline__ void cvt4(const float4 s, uint2& hi, uint2& lo) {
    const u16 h0 = f2bf(s.x), h1 = f2bf(s.y), h2 = f2bf(s.z), h3 = f2bf(s.w);
    hi = make_uint2((unsigned)h0 | ((unsigned)h1 << 16), (unsigned)h2 | ((unsigned)h3 << 16));
    const u16 l0 = f2bf(s.x - bf2f(h0)), l1 = f2bf(s.y - bf2f(h1));
    const u16 l2 = f2bf(s.z - bf2f(h2)), l3 = f2bf(s.w - bf2f(h3));
    lo = make_uint2((unsigned)l0 | ((unsigned)l1 << 16), (unsigned)l2 | ((unsigned)l3 << 16));
}
// hi-only variant (internal activations)
__device__ __forceinline__ uint2 cvt4hi(const float4 s) {
    const u16 h0 = f2bf(s.x), h1 = f2bf(s.y), h2 = f2bf(s.z), h3 = f2bf(s.w);
    return make_uint2((unsigned)h0 | ((unsigned)h1 << 16), (unsigned)h2 | ((unsigned)h3 << 16));
}

// broadcast edge-attr value from lane (16q + K) within each 16-lane group, then FMA.
template<int K>
__device__ __forceinline__ void bcast16_fma(const float av, const vf2* __restrict__ wr, vf2& m) {
    const float a = __uint_as_float((unsigned)__builtin_amdgcn_ds_swizzle(
        (int)__float_as_uint(av), (K << 5) | 0x10));
    m = fma2(splat2(a), wr[K], m);
    if constexpr (K + 1 < EF) bcast16_fma<K + 1>(av, wr, m);
}

// ---------------- CSR build: histogram -> scan -> scatter(idx) -> gather-permute ----------------
// R5 lesson: do NOT fuse the ea copy into scatter (scattered 64 B writes ~2x scattered reads).
// R7 lesson: do NOT fuse e2's gather into n2 (gather MLP collapses 16x; 225 us vs 166 serial).
__global__ __launch_bounds__(256) void hist_kernel(const int* __restrict__ ei, int* __restrict__ cnt)
{
    const int i = blockIdx.x * 256 + threadIdx.x;
    if (i < NEDGES) atomicAdd(&cnt[ei[NEDGES + i]], 1);
}

__global__ __launch_bounds__(1024) void scan_kernel(const int* __restrict__ cnt, int* __restrict__ rs)
{
    __shared__ int s[1024];
    const int t = threadIdx.x;
    int loc[64];
    int tot = 0;
    const int4* c4 = (const int4*)(cnt + t * 64);
    #pragma unroll
    for (int j = 0; j < 16; ++j) {
        const int4 v = c4[j];
        loc[4*j+0] = v.x; loc[4*j+1] = v.y; loc[4*j+2] = v.z; loc[4*j+3] = v.w;
        tot += v.x + v.y + v.z + v.w;
    }
    s[t] = tot;
    __syncthreads();
    for (int off = 1; off < 1024; off <<= 1) {
        const int v = (t >= off) ? s[t - off] : 0;
        __syncthreads();
        s[t] += v;
        __syncthreads();
    }
    int run = s[t] - tot;
    #pragma unroll
    for (int j = 0; j < 64; ++j) { rs[t * 64 + j] = run; run += loc[j]; }
    if (t == 0) rs[NNODES] = NEDGES;
}

__global__ __launch_bounds__(256) void scatter_kernel(
    const int* __restrict__ ei, const int* __restrict__ rs, int* __restrict__ fill,
    int* __restrict__ ssrc, int* __restrict__ seidx)
{
    const int i = blockIdx.x * 256 + threadIdx.x;
    if (i < NEDGES) {
        const int d = ei[NEDGES + i];
        const int pos = rs[d] + atomicAdd(&fill[d], 1);
        ssrc[pos]  = ei[i];
        seidx[pos] = i;
    }
}

// R11: sea stored as packed bf16 (32 MB vs 64 MB) -- third application of the bf16-mirror
// pattern (h: R5, x: R10, both zero absmax change).  Gather-read ea f32, write bf16.
__global__ __launch_bounds__(256) void permute_kernel(
    const int* __restrict__ seidx, const float* __restrict__ ea, u16* __restrict__ sea16)
{
    const int t = blockIdx.x * 256 + threadIdx.x;
    const int e = t >> 2, part = t & 3;
    const int idx = seidx[e];
    const float4 v = ((const float4*)ea)[(size_t)idx * 4 + part];
    ((uint2*)sea16)[(size_t)e * 4 + part] = cvt4hi(v);
}

// x -> bf16 mirror (consumed by e1's gather; n1 still reads f32 x)
__global__ __launch_bounds__(256) void cvtx_kernel(const float* __restrict__ x, u16* __restrict__ x16)
{
    const int i = blockIdx.x * 256 + threadIdx.x;   // one float4 -> uint2 per thread
    const float4 v = ((const float4*)x)[i];
    ((uint2*)x16)[i] = cvt4hi(v);
}

// ---------------- weight packing (all 6 matrices, one launch) ----------------
__global__ __launch_bounds__(256) void pack_all_kernel(
    const float* __restrict__ w0, const float* __restrict__ w1, const float* __restrict__ w2,
    const float* __restrict__ w3, const float* __restrict__ w4, const float* __restrict__ w5,
    u16* __restrict__ pw)
{
    const int bid = blockIdx.x;
    const float* W; int KB, seg, sbase;
    if (bid < 16) { W = w0; KB = 1; seg = 0; sbase = 0; }
    else {
        const int i = (bid - 16) >> 6;
        seg = i + 1; sbase = 16 + i * 64; KB = 4;
        W = (i == 0) ? w1 : (i == 1) ? w2 : (i == 2) ? w3 : (i == 3) ? w4 : w5;
    }
    const int t = (bid - sbase) * 256 + threadIdx.x;
    const int j = t & 7, lane = (t >> 3) & 63, rest = t >> 9;
    const int kb = rest % KB, fb = rest / KB;
    if (fb >= 8) return;
    const int k = kb * 32 + (lane >> 4) * 8 + j;
    const int f = fb * 16 + (lane & 15);
    const float val = W[k * HD + f];
    const u16 h = f2bf(val);
    u16* dst = pw + seg * 32768;
    dst[t] = h;
    dst[16384 + t] = f2bf(val - bf2f(h));
}

// ---------------- edge layer 1 (gather): 4 nodes per wave, bf16 x + bf16 sea ----------------
__global__ __launch_bounds__(256) void e1_agg_kernel(
    const u16* __restrict__ x16, const int* __restrict__ rs,
    const int* __restrict__ ssrc, const u16* __restrict__ sea16,
    const float* __restrict__ w, const float* __restrict__ b, float* __restrict__ agg)
{
    const int tid  = threadIdx.x;
    const int lane = tid & 63;
    const int p    = lane & 15;          // feature pair: f = 2p, 2p+1
    const int q    = lane >> 4;          // edge chain 0..3
    const int node0 = (blockIdx.x * 4 + (tid >> 6)) * 4;   // 4 nodes per wave
    vf2 wr[EF];
    #pragma unroll
    for (int k = 0; k < EF; ++k) wr[k] = *(const vf2*)&w[k * NF + p * 2];
    const vf2 bias = *(const vf2*)&b[p * 2];
    // prefetch CSR bounds for all 4 nodes (contiguous scalar run)
    int rsv[5];
    #pragma unroll
    for (int i = 0; i < 5; ++i) rsv[i] = __builtin_amdgcn_readfirstlane(rs[node0 + i]);
    // prefetch first-window ssrc for all 4 nodes (independent loads in flight)
    int srcLn[4];
    #pragma unroll
    for (int n = 0; n < 4; ++n) {
        const int nw0 = min(rsv[n + 1] - rsv[n], 64);
        srcLn[n] = (lane < nw0) ? ssrc[rsv[n] + lane] : 0;
    }
    #pragma unroll
    for (int n = 0; n < 4; ++n) {
        const int beg = rsv[n], end = rsv[n + 1];
        vf2 acc = {0.0f, 0.0f};
        int srcL = srcLn[n];
        for (int wnd = beg; wnd < end; wnd += 64) {
            const int nw = min(end - wnd, 64);
            if (wnd != beg) srcL = (lane < nw) ? ssrc[wnd + lane] : 0;  // rare (deg > 64)
            const u16* sbase = sea16 + (size_t)wnd * EF;
            int blk = 0;
            // full 16-edge blocks
            for (; blk + 16 <= nw; blk += 16) {
                float av[4];
                #pragma unroll
                for (int u = 0; u < 4; ++u)
                    av[u] = bf2f(sbase[blk * EF + u * 64 + lane]);  // lane 16q+k holds ea[edge blk+u*4+q][k]
                unsigned xv[4];
                #pragma unroll
                for (int u = 0; u < 4; ++u) {
                    const int sA = __shfl(srcL, blk + u * 4 + q, 64);
                    xv[u] = *(const unsigned*)((const char*)x16 + (((unsigned)sA << 6) + (unsigned)p * 4));
                }
                #pragma unroll
                for (int u = 0; u < 4; ++u) {
                    vf2 m = bias;
                    bcast16_fma<0>(av[u], wr, m);
                    acc += max2(up2(xv[u]) + m, splat2(0.0f));
                }
            }
            // remainder block (0..15 edges), slots skipped by uniform scalar branch
            const int nrem = nw - blk;
            if (nrem > 0) {
                #pragma unroll
                for (int u = 0; u < 4; ++u) {
                    if (u * 4 >= nrem) break;                  // nrem wave-uniform -> scalar skip
                    const int myidx = u * 4 + q;
                    const bool valid = myidx < nrem;
                    const float av = valid ? bf2f(sbase[blk * EF + u * 64 + lane]) : 0.0f;
                    const int sA = __shfl(srcL, min(blk + myidx, nw - 1), 64);  // clamped, real node
                    const unsigned xv = *(const unsigned*)((const char*)x16 + (((unsigned)sA << 6) + (unsigned)p * 4));
                    vf2 m = bias;
                    bcast16_fma<0>(av, wr, m);
                    if (valid) acc += max2(up2(xv) + m, splat2(0.0f));
                }
            }
        }
        acc[0] += __shfl_xor(acc[0], 16, 64); acc[1] += __shfl_xor(acc[1], 16, 64);
        acc[0] += __shfl_xor(acc[0], 32, 64); acc[1] += __shfl_xor(acc[1], 32, 64);
        if (lane < 16) *(vf2*)&agg[(size_t)(node0 + n) * NF + p * 2] = acc;
    }
}

// ---------------- edge layer 2 (gather): bf16 h mirror + bf16 sea, 4-edge quad pipeline ----------
// sea dwords are wave-uniform (s_load); the <<16 / &0xFFFF0000 unpack of uniform values
// lowers to SALU, not the 52%-busy VALU pipe.  k-order preserved: dword j = attrs {2j lo, 2j+1 hi}.
__global__ __launch_bounds__(256) void e2_agg_kernel(
    const u16* __restrict__ h16, const int* __restrict__ rs,
    const int* __restrict__ ssrc, const u16* __restrict__ sea16,
    const float* __restrict__ w, const float* __restrict__ b, float* __restrict__ agg)
{
    const int tid  = threadIdx.x;
    const int lane = tid & 63;
    const unsigned foff = (unsigned)lane * 4;    // byte offset of packed feature pair (bf16)
    const int node = blockIdx.x * 4 + (tid >> 6);
    vf2 wr[EF];
    #pragma unroll
    for (int k = 0; k < EF; ++k) wr[k] = *(const vf2*)&w[k * HD + lane * 2];
    const vf2 bias = *(const vf2*)&b[lane * 2];
    const int beg = __builtin_amdgcn_readfirstlane(rs[node]);
    const int end = __builtin_amdgcn_readfirstlane(rs[node + 1]);
    vf2 acc = {0.0f, 0.0f};
    int e = beg;
    #define LDH(s) (*(const unsigned*)((const char*)h16 + (((unsigned)(s) << 8) + foff)))
    #define SEA_FMA(mv, base, j) \
        { const unsigned d_ = (base)[j]; \
          mv = fma2(splat2(__uint_as_float(d_ << 16)), wr[2*(j)], mv); \
          mv = fma2(splat2(__uint_as_float(d_ & 0xFFFF0000u)), wr[2*(j)+1], mv); }
    if (e + 4 <= end) {
        // prologue: load quad 0
        int s0 = ssrc[e], s1 = ssrc[e + 1], s2 = ssrc[e + 2], s3 = ssrc[e + 3];
        unsigned d0 = LDH(s0), d1 = LDH(s1), d2 = LDH(s2), d3 = LDH(s3);
        for (; e + 8 <= end; e += 4) {
            // issue next quad's index + h loads (always in-bounds: e+7 <= end-1)
            const int t0 = ssrc[e + 4], t1 = ssrc[e + 5], t2 = ssrc[e + 6], t3 = ssrc[e + 7];
            const unsigned g0 = LDH(t0), g1 = LDH(t1), g2 = LDH(t2), g3 = LDH(t3);
            // compute current quad; sea dwords are uniform -> s_load + SALU unpack
            const unsigned* a0 = (const unsigned*)(sea16 + (size_t)e * EF);  // 8 dwords/edge
            vf2 m0 = bias, m1 = bias, m2 = bias, m3 = bias;
            #pragma unroll
            for (int j = 0; j < 8; ++j) {
                SEA_FMA(m0, a0, j);
                SEA_FMA(m1, a0 + 8, j);
            }
            acc += max2(up2(d0) + m0, splat2(0.0f));
            acc += max2(up2(d1) + m1, splat2(0.0f));
            #pragma unroll
            for (int j = 0; j < 8; ++j) {
                SEA_FMA(m2, a0 + 16, j);
                SEA_FMA(m3, a0 + 24, j);
            }
            acc += max2(up2(d2) + m2, splat2(0.0f));
            acc += max2(up2(d3) + m3, splat2(0.0f));
            s0 = t0; s1 = t1; s2 = t2; s3 = t3;
            d0 = g0; d1 = g1; d2 = g2; d3 = g3;
        }
        // drain: compute the last preloaded quad
        {
            const unsigned* a0 = (const unsigned*)(sea16 + (size_t)e * EF);
            vf2 m0 = bias, m1 = bias, m2 = bias, m3 = bias;
            #pragma unroll
            for (int j = 0; j < 8; ++j) {
                SEA_FMA(m0, a0, j);
                SEA_FMA(m1, a0 + 8, j);
            }
            acc += max2(up2(d0) + m0, splat2(0.0f));
            acc += max2(up2(d1) + m1, splat2(0.0f));
            #pragma unroll
            for (int j = 0; j < 8; ++j) {
                SEA_FMA(m2, a0 + 16, j);
                SEA_FMA(m3, a0 + 24, j);
            }
            acc += max2(up2(d2) + m2, splat2(0.0f));
            acc += max2(up2(d3) + m3, splat2(0.0f));
            e += 4;
        }
    }
    // remainder 0..3 edges
    for (; e < end; ++e) {
        const int sA = ssrc[e];
        const unsigned dA = LDH(sA);
        const unsigned* aA = (const unsigned*)(sea16 + (size_t)e * EF);
        vf2 mA = bias;
        #pragma unroll
        for (int j = 0; j < 8; ++j) SEA_FMA(mA, aA, j);
        acc += max2(up2(dA) + mA, splat2(0.0f));
    }
    #undef SEA_FMA
    #undef LDH
    *(vf2*)&agg[(size_t)node * HD + lane * 2] = acc;
}

// ---------------- MFMA node-GEMM building blocks ----------------
#define ROW128 272   // 128 bf16 = 256 B + 16 pad
#define ROW32  80    // 32 bf16 = 64 B + 16 pad

// layer consuming internal ACTIVATIONS (hi-only B): 2 MFMAs per (fb,kb).
// R9: double-buffered weight prefetch -- keeps 8 independent weight loads in
// flight under each MFMA cluster (was L2-latency serial before; -10 us total).
__device__ __forceinline__ void mfma_layer128_act(
    const unsigned char* __restrict__ aH,
    const u16* __restrict__ wH, const u16* __restrict__ wL,
    const float* __restrict__ bias, int lane, vf4* __restrict__ acc)
{
    const int quad = lane >> 4, fm = lane & 15;
    int4 Bh[4];
    #pragma unroll
    for (int kb = 0; kb < 4; ++kb)
        Bh[kb] = *(const int4*)(aH + fm * ROW128 + kb * 64 + quad * 16);
    int4 wh0[4], wl0[4], wh1[4], wl1[4];
    #pragma unroll
    for (int kb = 0; kb < 4; ++kb) {
        wh0[kb] = *(const int4*)(wH + ((0 * 4 + kb) * 64 + lane) * 8);
        wl0[kb] = *(const int4*)(wL + ((0 * 4 + kb) * 64 + lane) * 8);
    }
    #pragma unroll
    for (int fbp = 0; fbp < 4; ++fbp) {
        const int fbA = fbp * 2, fbB = fbp * 2 + 1;
        // issue fbB's loads before fbA's MFMAs
        #pragma unroll
        for (int kb = 0; kb < 4; ++kb) {
            wh1[kb] = *(const int4*)(wH + ((fbB * 4 + kb) * 64 + lane) * 8);
            wl1[kb] = *(const int4*)(wL + ((fbB * 4 + kb) * 64 + lane) * 8);
        }
        {
            const float4 bv = *(const float4*)&bias[fbA * 16 + quad * 4];
            vf4 a = {bv.x, bv.y, bv.z, bv.w};
            #pragma unroll
            for (int kb = 0; kb < 4; ++kb) {
                a = __builtin_amdgcn_mfma_f32_16x16x32_bf16(BC8(wl0[kb]), BC8(Bh[kb]), a, 0, 0, 0);
                a = __builtin_amdgcn_mfma_f32_16x16x32_bf16(BC8(wh0[kb]), BC8(Bh[kb]), a, 0, 0, 0);
            }
            acc[fbA] = a;
        }
        // issue next pair's fbA loads before fbB's MFMAs
        if (fbp < 3) {
            #pragma unroll
            for (int kb = 0; kb < 4; ++kb) {
                wh0[kb] = *(const int4*)(wH + (((fbA + 2) * 4 + kb) * 64 + lane) * 8);
                wl0[kb] = *(const int4*)(wL + (((fbA + 2) * 4 + kb) * 64 + lane) * 8);
            }
        }
        {
            const float4 bv = *(const float4*)&bias[fbB * 16 + quad * 4];
            vf4 a = {bv.x, bv.y, bv.z, bv.w};
            #pragma unroll
            for (int kb = 0; kb < 4; ++kb) {
                a = __builtin_amdgcn_mfma_f32_16x16x32_bf16(BC8(wl1[kb]), BC8(Bh[kb]), a, 0, 0, 0);
                a = __builtin_amdgcn_mfma_f32_16x16x32_bf16(BC8(wh1[kb]), BC8(Bh[kb]), a, 0, 0, 0);
            }
            acc[fbB] = a;
        }
    }
}

__device__ __forceinline__ void mfma_layer32_in(
    const unsigned char* __restrict__ aH, const unsigned char* __restrict__ aL,
    const u16* __restrict__ wH, const u16* __restrict__ wL,
    const float* __restrict__ bias, int lane, vf4* __restrict__ acc)
{
    const int quad = lane >> 4, fm = lane & 15;
    const int4 Bh = *(const int4*)(aH + fm * ROW32 + quad * 16);
    const int4 Bl = *(const int4*)(aL + fm * ROW32 + quad * 16);
    #pragma unroll
    for (int fb = 0; fb < 8; ++fb) {
        const float4 bv = *(const float4*)&bias[fb * 16 + quad * 4];
        vf4 a = {bv.x, bv.y, bv.z, bv.w};
        const int4 wh = *(const int4*)(wH + (fb * 64 + lane) * 8);
        const int4 wl = *(const int4*)(wL + (fb * 64 + lane) * 8);
        a = __builtin_amdgcn_mfma_f32_16x16x32_bf16(BC8(wh), BC8(Bl), a, 0, 0, 0);
        a = __builtin_amdgcn_mfma_f32_16x16x32_bf16(BC8(wl), BC8(Bh), a, 0, 0, 0);
        a = __builtin_amdgcn_mfma_f32_16x16x32_bf16(BC8(wh), BC8(Bh), a, 0, 0, 0);
        acc[fb] = a;
    }
}

// apply leaky, write hi-only activations to LDS (acc updated to post-activation values)
__device__ __forceinline__ void store_act_hi(
    unsigned char* __restrict__ aH, int lane, vf4* __restrict__ acc)
{
    const int quad = lane >> 4, fm = lane & 15;
    #pragma unroll
    for (int fb = 0; fb < 8; ++fb) {
        const float4 s = {leakyf(acc[fb][0]), leakyf(acc[fb][1]), leakyf(acc[fb][2]), leakyf(acc[fb][3])};
        acc[fb][0] = s.x; acc[fb][1] = s.y; acc[fb][2] = s.z; acc[fb][3] = s.w;
        *(uint2*)(aH + fm * ROW128 + fb * 32 + quad * 8) = cvt4hi(s);
    }
}

// ---------------- node MLP layer 1 (MFMA, wave-private slab, NO block barriers) ----------------
// Additionally writes the bf16 mirror of h (hb16) consumed by e2's gather.
__global__ __launch_bounds__(256) void n1_kernel(
    const float* __restrict__ x, const float* __restrict__ agg,
    const u16* __restrict__ w1h, const u16* __restrict__ w1l, const float* __restrict__ b1,
    const u16* __restrict__ w2h, const u16* __restrict__ w2l, const float* __restrict__ b2,
    float* __restrict__ hout, u16* __restrict__ hb16)
{
    __shared__ __align__(16) unsigned char smem[4][2560 + 16 * ROW128];
    const int tid = threadIdx.x, lane = tid & 63, wid = tid >> 6;
    const int quad = lane >> 4, fm = lane & 15;
    const int tile = blockIdx.x * 4 + wid;
    unsigned char* inH = smem[wid];
    unsigned char* inL = inH + 16 * ROW32;
    unsigned char* aH  = inH + 2560;
    const size_t base = (size_t)tile * 16 * NF;
    #pragma unroll
    for (int i = 0; i < 2; ++i) {
        const int flat = i * 64 + lane;
        const int node = flat >> 3, kq = flat & 7;
        const float4 xv = *(const float4*)&x[base + node * NF + kq * 4];
        const float4 av = *(const float4*)&agg[base + node * NF + kq * 4];
        const float4 s = {xv.x + av.x, xv.y + av.y, xv.z + av.z, xv.w + av.w};
        uint2 phi, plo;
        cvt4(s, phi, plo);
        *(uint2*)(inH + node * ROW32 + kq * 8) = phi;
        *(uint2*)(inL + node * ROW32 + kq * 8) = plo;
    }
    WB();
    vf4 acc[8];
    mfma_layer32_in(inH, inL, w1h, w1l, b1, lane, acc);
    WB();
    store_act_hi(aH, lane, acc);
    WB();
    mfma_layer128_act(aH, w2h, w2l, b2, lane, acc);
    const size_t ob = (size_t)tile * 16 * HD;
    #pragma unroll
    for (int fb = 0; fb < 8; ++fb) {
        const float4 o = {fmaxf(acc[fb][0], 0.0f), fmaxf(acc[fb][1], 0.0f),
                          fmaxf(acc[fb][2], 0.0f), fmaxf(acc[fb][3], 0.0f)};
        *(float4*)&hout[ob + fm * HD + fb * 16 + quad * 4] = o;
        // bf16 mirror: row (tile*16+fm), dword d holds features 2d | 2d+1<<16
        *(uint2*)((unsigned char*)hb16 + (((size_t)(tile * 16 + fm)) << 8) + fb * 32 + quad * 8)
            = cvt4hi(o);
    }
}

// ---- node layer 2 + pooling + node-score head (MFMA, wave-private slab, NO block barriers) ----
__global__ __launch_bounds__(256) void n2_kernel(
    const float* __restrict__ h, const float* __restrict__ agg,
    const u16* __restrict__ w1h, const u16* __restrict__ w1l, const float* __restrict__ b1,
    const u16* __restrict__ w2h, const u16* __restrict__ w2l, const float* __restrict__ b2,
    const u16* __restrict__ m1h, const u16* __restrict__ m1l, const float* __restrict__ nb1,
    const u16* __restrict__ m2h, const u16* __restrict__ m2l, const float* __restrict__ nb2,
    const float* __restrict__ nw3, const float* __restrict__ nb3,
    float* __restrict__ pooled, float* __restrict__ scores)
{
    __shared__ __align__(16) unsigned char smem[4][16 * ROW128];
    const int tid = threadIdx.x, lane = tid & 63, wid = tid >> 6;
    const int quad = lane >> 4, fm = lane & 15;
    const int tile = blockIdx.x * 4 + wid;
    unsigned char* aH = smem[wid];
    const size_t base = (size_t)tile * 16 * HD;
    #pragma unroll
    for (int i = 0; i < 8; ++i) {
        const int flat = i * 64 + lane;
        const int node = flat >> 5, kq = flat & 31;
        const float4 hv = *(const float4*)&h[base + node * HD + kq * 4];
        const float4 av = *(const float4*)&agg[base + node * HD + kq * 4];
        const float4 s = {hv.x + av.x, hv.y + av.y, hv.z + av.z, hv.w + av.w};
        *(uint2*)(aH + node * ROW128 + kq * 8) = cvt4hi(s);
    }
    WB();
    vf4 acc[8];
    mfma_layer128_act(aH, w1h, w1l, b1, lane, acc);       // hi-only input, hi+lo weights
    WB();
    store_act_hi(aH, lane, acc);
    WB();
    mfma_layer128_act(aH, w2h, w2l, b2, lane, acc);
    WB();
    store_act_hi(aH, lane, acc);                          // acc now holds h2 (leaky'd)
    {
        const int g = tile >> 6;
        #pragma unroll
        for (int fb = 0; fb < 8; ++fb) {
            vf4 t = acc[fb];
            #pragma unroll
            for (int off = 1; off < 16; off <<= 1) {
                t[0] += __shfl_xor(t[0], off, 64);
                t[1] += __shfl_xor(t[1], off, 64);
                t[2] += __shfl_xor(t[2], off, 64);
                t[3] += __shfl_xor(t[3], off, 64);
            }
            #pragma unroll
            for (int r = 0; r < 4; ++r) {
                const int item = fb * 4 + r;
                if (fm == (item >> 1))
                    atomicAdd(&pooled[g * HD + fb * 16 + quad * 4 + r], t[r]);
            }
        }
    }
    WB();
    mfma_layer128_act(aH, m1h, m1l, nb1, lane, acc);
    WB();
    store_act_hi(aH, lane, acc);
    WB();
    mfma_layer128_act(aH, m2h, m2l, nb2, lane, acc);
    float v = 0.0f;
    #pragma unroll
    for (int fb = 0; fb < 8; ++fb) {
        const float4 w3v = *(const float4*)&nw3[fb * 16 + quad * 4];
        v += leakyf(acc[fb][0]) * w3v.x + leakyf(acc[fb][1]) * w3v.y
           + leakyf(acc[fb][2]) * w3v.z + leakyf(acc[fb][3]) * w3v.w;
    }
    v += __shfl_xor(v, 16, 64);
    v += __shfl_xor(v, 32, 64);
    if (lane < 16) {
        const int node = tile * 16 + fm;
        const float s = v + nb3[0];
        scores[(node & 63) * NPER + (node >> 6)] = 1.0f / (1.0f + expf(-s));
    }
}

// ---------------- action head: pooled mean -> MLP -> softmax ----------------
__global__ __launch_bounds__(128) void act_kernel(
    const float* __restrict__ pooled,
    const float* __restrict__ w1, const float* __restrict__ b1,
    const float* __restrict__ w2, const float* __restrict__ b2,
    float* __restrict__ out)
{
    __shared__ __align__(16) float p[HD];
    __shared__ float a1[HD];
    __shared__ float z[NACT];
    __shared__ float red2[2];
    const int g = blockIdx.x;
    const int tid = threadIdx.x;
    p[tid] = pooled[g * HD + tid] * (1.0f / NPER);
    __syncthreads();
    float acc = b1[tid];
    for (int k = 0; k < HD; ++k) acc = fmaf(p[k], w1[k * HD + tid], acc);
    a1[tid] = leakyf(acc);
    __syncthreads();
    if (tid < NACT) {
        float a2 = b2[tid];
        for (int k = 0; k < HD; ++k) a2 = fmaf(a1[k], w2[k * NACT + tid], a2);
        z[tid] = leakyf(a2);
    }
    __syncthreads();
    if (tid == 0) {
        float m = z[0];
        for (int i = 1; i < NACT; ++i) m = fmaxf(m, z[i]);
        red2[0] = m;
    }
    __syncthreads();
    if (tid < NACT) z[tid] = expf(z[tid] - red2[0]);
    __syncthreads();
    if (tid == 0) {
        float s = 0.0f;
        for (int i = 0; i < NACT; ++i) s += z[i];
        red2[1] = s;
    }
    __syncthreads();
    if (tid < NACT) out[g * NACT + tid] = z[tid] / red2[1];
}

extern "C" void kernel_launch(void* const* d_in, const int* in_sizes, int n_in,
                              void* d_out, int out_size, void* d_ws, size_t ws_size,
                              hipStream_t stream)
{
    const float* x    = (const float*)d_in[0];
    const int*   ei   = (const int*)d_in[1];     // int32
    const float* ea   = (const float*)d_in[2];
    const float* e1w  = (const float*)d_in[3];
    const float* e1b  = (const float*)d_in[4];
    const float* c1w1 = (const float*)d_in[5];
    const float* c1b1 = (const float*)d_in[6];
    const float* c1w2 = (const float*)d_in[7];
    const float* c1b2 = (const float*)d_in[8];
    const float* e2w  = (const float*)d_in[9];
    const float* e2b  = (const float*)d_in[10];
    const float* c2w1 = (const float*)d_in[11];
    const float* c2b1 = (const float*)d_in[12];
    const float* c2w2 = (const float*)d_in[13];
    const float* c2b2 = (const float*)d_in[14];
    const float* aw1  = (const float*)d_in[15];
    const float* ab1  = (const float*)d_in[16];
    const float* aw2  = (const float*)d_in[17];
    const float* ab2  = (const float*)d_in[18];
    const float* nw1  = (const float*)d_in[19];
    const float* nb1  = (const float*)d_in[20];
    const float* nw2  = (const float*)d_in[21];
    const float* nb2  = (const float*)d_in[22];
    const float* nw3  = (const float*)d_in[23];
    const float* nb3  = (const float*)d_in[24];

    float* out = (float*)d_out;
    char*  ws  = (char*)d_ws;
    const size_t MB = 1024 * 1024;
    float* h      = (float*)(ws);
    float* agg2   = (float*)(ws + 32  * MB);
    int*   seidx  = (int*)  (ws + 32  * MB);     // dead before e2_agg writes agg2
    u16*   sea16  = (u16*)  (ws + 64  * MB);     // 32 MB packed bf16 edge attrs (sorted)
    float* agg1   = (float*)(ws + 128 * MB);
    float* pooled = (float*)(ws + 136 * MB);
    u16*   pw     = (u16*)  (ws + 136 * MB + 64 * 1024);
    int*   cnt    = (int*)  (ws + 137 * MB);
    int*   fill   = (int*)  (ws + 137 * MB + 256 * 1024);
    int*   rs     = (int*)  (ws + 139 * MB);
    int*   ssrc   = (int*)  (ws + 140 * MB);
    u16*   hb16   = (u16*)  (ws + 144 * MB);     // 16 MB bf16 mirror of h
    u16*   x16    = (u16*)  (ws + 160 * MB);     // 4 MB bf16 mirror of x

    u16* p_c1w1 = pw;
    u16* p_c1w2 = pw + 1 * 32768;
    u16* p_c2w1 = pw + 2 * 32768;
    u16* p_c2w2 = pw + 3 * 32768;
    u16* p_nw1  = pw + 4 * 32768;
    u16* p_nw2  = pw + 5 * 32768;

    hipMemsetAsync(cnt,    0, 2 * NNODES * sizeof(int), stream);
    hipMemsetAsync(pooled, 0, (size_t)NB * HD * sizeof(float), stream);

    pack_all_kernel<<<336, 256, 0, stream>>>(c1w1, c1w2, c2w1, c2w2, nw1, nw2, pw);
    cvtx_kernel<<<NNODES * NF / 4 / 256, 256, 0, stream>>>(x, x16);

    hist_kernel<<<NEDGES / 256, 256, 0, stream>>>(ei, cnt);
    scan_kernel<<<1, 1024, 0, stream>>>(cnt, rs);
    scatter_kernel<<<NEDGES / 256, 256, 0, stream>>>(ei, rs, fill, ssrc, seidx);
    permute_kernel<<<NEDGES / 64, 256, 0, stream>>>(seidx, ea, sea16);

    e1_agg_kernel<<<NNODES / 16, 256, 0, stream>>>(x16, rs, ssrc, sea16, e1w, e1b, agg1);
    n1_kernel<<<NNODES / 64, 256, 0, stream>>>(x, agg1,
                                               p_c1w1, p_c1w1 + 16384, c1b1,
                                               p_c1w2, p_c1w2 + 16384, c1b2, h, hb16);
    e2_agg_kernel<<<NNODES / 4, 256, 0, stream>>>(hb16, rs, ssrc, sea16, e2w, e2b, agg2);
    n2_kernel<<<NNODES / 64, 256, 0, stream>>>(h, agg2,
                                               p_c2w1, p_c2w1 + 16384, c2b1,
                                               p_c2w2, p_c2w2 + 16384, c2b2,
                                               p_nw1,  p_nw1  + 16384, nb1,
                                               p_nw2,  p_nw2  + 16384, nb2,
                                               nw3, nb3, pooled, out + NB * NACT);
    act_kernel<<<NB, 128, 0, stream>>>(pooled, aw1, ab1, aw2, ab2, out);
}

// Round 12
// 500.114 us; speedup vs baseline: 1.0791x; 1.0791x over previous
//
#include <hip/hip_runtime.h>
#include <math.h>

#define NNODES 65536
#define NEDGES 1048576
#define NF 32
#define EF 16
#define HD 128
#define NACT 10
#define NB 64
#define NPER 1024

typedef unsigned short u16;
typedef float  vf2  __attribute__((ext_vector_type(2)));
typedef float  vf4  __attribute__((ext_vector_type(4)));
typedef __bf16 vbf8 __attribute__((ext_vector_type(8)));
#define BC8(v) __builtin_bit_cast(vbf8, v)
#define WB() __builtin_amdgcn_wave_barrier()   // compile-time phase fence, no HW cost

__device__ __forceinline__ float leakyf(float v) { return v > 0.0f ? v : 0.01f * v; }
__device__ __forceinline__ vf2 fma2(vf2 a, vf2 b, vf2 c) { return __builtin_elementwise_fma(a, b, c); }
__device__ __forceinline__ vf2 max2(vf2 a, vf2 b) { return __builtin_elementwise_max(a, b); }
__device__ __forceinline__ vf2 splat2(float s) { vf2 r = {s, s}; return r; }

__device__ __forceinline__ u16 f2bf(float x) {
    unsigned u = __float_as_uint(x);
    return (u16)((u + 0x7FFFu + ((u >> 16) & 1u)) >> 16);
}
__device__ __forceinline__ float bf2f(u16 h) { return __uint_as_float(((unsigned)h) << 16); }

// unpack one dword of 2 packed bf16 (features 2i [low], 2i+1 [high]) to vf2
__device__ __forceinline__ vf2 up2(unsigned d) {
    vf2 r = { __uint_as_float(d << 16), __uint_as_float(d & 0xFFFF0000u) };
    return r;
}

// split f32x4 into bf16-hi and bf16-lo packed pairs (hi + lo ~= full f32 precision)
__device__ __forceinline__ void cvt4(const float4 s, uint2& hi, uint2& lo) {
    const u16 h0 = f2bf(s.x), h1 = f2bf(s.y), h2 = f2bf(s.z), h3 = f2bf(s.w);
    hi = make_uint2((unsigned)h0 | ((unsigned)h1 << 16), (unsigned)h2 | ((unsigned)h3 << 16));
    const u16 l0 = f2bf(s.x - bf2f(h0)), l1 = f2bf(s.y - bf2f(h1));
    const u16 l2 = f2bf(s.z - bf2f(h2)), l3 = f2bf(s.w - bf2f(h3));
    lo = make_uint2((unsigned)l0 | ((unsigned)l1 << 16), (unsigned)l2 | ((unsigned)l3 << 16));
}
// hi-only variant (internal activations)
__device__ __forceinline__ uint2 cvt4hi(const float4 s) {
    const u16 h0 = f2bf(s.x), h1 = f2bf(s.y), h2 = f2bf(s.z), h3 = f2bf(s.w);
    return make_uint2((unsigned)h0 | ((unsigned)h1 << 16), (unsigned)h2 | ((unsigned)h3 << 16));
}

// broadcast edge-attr value from lane (16q + K) within each 16-lane group, then FMA.
template<int K>
__device__ __forceinline__ void bcast16_fma(const float av, const vf2* __restrict__ wr, vf2& m) {
    const float a = __uint_as_float((unsigned)__builtin_amdgcn_ds_swizzle(
        (int)__float_as_uint(av), (K << 5) | 0x10));
    m = fma2(splat2(a), wr[K], m);
    if constexpr (K + 1 < EF) bcast16_fma<K + 1>(av, wr, m);
}

// ---------------- CSR build: histogram(+rank) -> scan -> scatter(no atomic) -> permute --------
// R5 lesson: do NOT fuse the ea copy into scatter (scattered 64 B writes ~2x scattered reads).
// R7 lesson: do NOT fuse e2's gather into n2 (gather MLP collapses 16x; 225 us vs 166 serial).
// R11 lesson: bf16-pack broadcast-scalar operands (sea) doubles VALU unpack work -- only
// gathered per-lane operands (h, x) benefit from the bf16-mirror pattern.
// R12: hist stores its atomicAdd return as rank[i]; scatter computes pos = rs[d] + rank[i]
// with NO RMW (the old fill atomic duplicated hist's work).  Within-node edge order stays
// atomic-order-nondeterministic exactly as before.
__global__ __launch_bounds__(256) void hist_kernel(const int* __restrict__ ei, int* __restrict__ cnt,
                                                   int* __restrict__ rank)
{
    const int i = blockIdx.x * 256 + threadIdx.x;
    if (i < NEDGES) rank[i] = atomicAdd(&cnt[ei[NEDGES + i]], 1);
}

__global__ __launch_bounds__(1024) void scan_kernel(const int* __restrict__ cnt, int* __restrict__ rs)
{
    __shared__ int s[1024];
    const int t = threadIdx.x;
    int loc[64];
    int tot = 0;
    const int4* c4 = (const int4*)(cnt + t * 64);
    #pragma unroll
    for (int j = 0; j < 16; ++j) {
        const int4 v = c4[j];
        loc[4*j+0] = v.x; loc[4*j+1] = v.y; loc[4*j+2] = v.z; loc[4*j+3] = v.w;
        tot += v.x + v.y + v.z + v.w;
    }
    s[t] = tot;
    __syncthreads();
    for (int off = 1; off < 1024; off <<= 1) {
        const int v = (t >= off) ? s[t - off] : 0;
        __syncthreads();
        s[t] += v;
        __syncthreads();
    }
    int run = s[t] - tot;
    #pragma unroll
    for (int j = 0; j < 64; ++j) { rs[t * 64 + j] = run; run += loc[j]; }
    if (t == 0) rs[NNODES] = NEDGES;
}

__global__ __launch_bounds__(256) void scatter_kernel(
    const int* __restrict__ ei, const int* __restrict__ rs, const int* __restrict__ rank,
    int* __restrict__ ssrc, int* __restrict__ seidx)
{
    const int i = blockIdx.x * 256 + threadIdx.x;
    if (i < NEDGES) {
        const int d = ei[NEDGES + i];
        const int pos = rs[d] + rank[i];     // no atomic: rank assigned during hist
        ssrc[pos]  = ei[i];
        seidx[pos] = i;
    }
}

__global__ __launch_bounds__(256) void permute_kernel(
    const int* __restrict__ seidx, const float* __restrict__ ea, float* __restrict__ sea)
{
    const int t = blockIdx.x * 256 + threadIdx.x;
    const int e = t >> 2, part = t & 3;
    const int idx = seidx[e];
    ((float4*)sea)[(size_t)e * 4 + part] = ((const float4*)ea)[(size_t)idx * 4 + part];
}

// x -> bf16 mirror (consumed by e1's gather; n1 still reads f32 x)
__global__ __launch_bounds__(256) void cvtx_kernel(const float* __restrict__ x, u16* __restrict__ x16)
{
    const int i = blockIdx.x * 256 + threadIdx.x;   // one float4 -> uint2 per thread
    const float4 v = ((const float4*)x)[i];
    ((uint2*)x16)[i] = cvt4hi(v);
}

// ---------------- weight packing (all 6 matrices, one launch) ----------------
__global__ __launch_bounds__(256) void pack_all_kernel(
    const float* __restrict__ w0, const float* __restrict__ w1, const float* __restrict__ w2,
    const float* __restrict__ w3, const float* __restrict__ w4, const float* __restrict__ w5,
    u16* __restrict__ pw)
{
    const int bid = blockIdx.x;
    const float* W; int KB, seg, sbase;
    if (bid < 16) { W = w0; KB = 1; seg = 0; sbase = 0; }
    else {
        const int i = (bid - 16) >> 6;
        seg = i + 1; sbase = 16 + i * 64; KB = 4;
        W = (i == 0) ? w1 : (i == 1) ? w2 : (i == 2) ? w3 : (i == 3) ? w4 : w5;
    }
    const int t = (bid - sbase) * 256 + threadIdx.x;
    const int j = t & 7, lane = (t >> 3) & 63, rest = t >> 9;
    const int kb = rest % KB, fb = rest / KB;
    if (fb >= 8) return;
    const int k = kb * 32 + (lane >> 4) * 8 + j;
    const int f = fb * 16 + (lane & 15);
    const float val = W[k * HD + f];
    const u16 h = f2bf(val);
    u16* dst = pw + seg * 32768;
    dst[t] = h;
    dst[16384 + t] = f2bf(val - bf2f(h));
}

// ---------------- edge layer 1 (gather): 4 nodes per wave, bf16 x mirror, f32 sea ----------------
__global__ __launch_bounds__(256) void e1_agg_kernel(
    const u16* __restrict__ x16, const int* __restrict__ rs,
    const int* __restrict__ ssrc, const float* __restrict__ sea,
    const float* __restrict__ w, const float* __restrict__ b, float* __restrict__ agg)
{
    const int tid  = threadIdx.x;
    const int lane = tid & 63;
    const int p    = lane & 15;          // feature pair: f = 2p, 2p+1
    const int q    = lane >> 4;          // edge chain 0..3
    const int node0 = (blockIdx.x * 4 + (tid >> 6)) * 4;   // 4 nodes per wave
    vf2 wr[EF];
    #pragma unroll
    for (int k = 0; k < EF; ++k) wr[k] = *(const vf2*)&w[k * NF + p * 2];
    const vf2 bias = *(const vf2*)&b[p * 2];
    // prefetch CSR bounds for all 4 nodes (contiguous scalar run)
    int rsv[5];
    #pragma unroll
    for (int i = 0; i < 5; ++i) rsv[i] = __builtin_amdgcn_readfirstlane(rs[node0 + i]);
    // prefetch first-window ssrc for all 4 nodes (independent loads in flight)
    int srcLn[4];
    #pragma unroll
    for (int n = 0; n < 4; ++n) {
        const int nw0 = min(rsv[n + 1] - rsv[n], 64);
        srcLn[n] = (lane < nw0) ? ssrc[rsv[n] + lane] : 0;
    }
    #pragma unroll
    for (int n = 0; n < 4; ++n) {
        const int beg = rsv[n], end = rsv[n + 1];
        vf2 acc = {0.0f, 0.0f};
        int srcL = srcLn[n];
        for (int wnd = beg; wnd < end; wnd += 64) {
            const int nw = min(end - wnd, 64);
            if (wnd != beg) srcL = (lane < nw) ? ssrc[wnd + lane] : 0;  // rare (deg > 64)
            const float* sbase = sea + (size_t)wnd * EF;
            int blk = 0;
            // full 16-edge blocks
            for (; blk + 16 <= nw; blk += 16) {
                float av[4];
                #pragma unroll
                for (int u = 0; u < 4; ++u)
                    av[u] = sbase[blk * EF + u * 64 + lane];   // lane 16q+k holds ea[edge blk+u*4+q][k]
                unsigned xv[4];
                #pragma unroll
                for (int u = 0; u < 4; ++u) {
                    const int sA = __shfl(srcL, blk + u * 4 + q, 64);
                    xv[u] = *(const unsigned*)((const char*)x16 + (((unsigned)sA << 6) + (unsigned)p * 4));
                }
                #pragma unroll
                for (int u = 0; u < 4; ++u) {
                    vf2 m = bias;
                    bcast16_fma<0>(av[u], wr, m);
                    acc += max2(up2(xv[u]) + m, splat2(0.0f));
                }
            }
            // remainder block (0..15 edges), slots skipped by uniform scalar branch
            const int nrem = nw - blk;
            if (nrem > 0) {
                #pragma unroll
                for (int u = 0; u < 4; ++u) {
                    if (u * 4 >= nrem) break;                  // nrem wave-uniform -> scalar skip
                    const int myidx = u * 4 + q;
                    const bool valid = myidx < nrem;
                    const float av = valid ? sbase[blk * EF + u * 64 + lane] : 0.0f;
                    const int sA = __shfl(srcL, min(blk + myidx, nw - 1), 64);  // clamped, real node
                    const unsigned xv = *(const unsigned*)((const char*)x16 + (((unsigned)sA << 6) + (unsigned)p * 4));
                    vf2 m = bias;
                    bcast16_fma<0>(av, wr, m);
                    if (valid) acc += max2(up2(xv) + m, splat2(0.0f));
                }
            }
        }
        acc[0] += __shfl_xor(acc[0], 16, 64); acc[1] += __shfl_xor(acc[1], 16, 64);
        acc[0] += __shfl_xor(acc[0], 32, 64); acc[1] += __shfl_xor(acc[1], 32, 64);
        if (lane < 16) *(vf2*)&agg[(size_t)(node0 + n) * NF + p * 2] = acc;
    }
}

// ---------------- edge layer 2 (gather): bf16 h mirror, f32 sea, 4-edge quad pipeline ----------
__global__ __launch_bounds__(256) void e2_agg_kernel(
    const u16* __restrict__ h16, const int* __restrict__ rs,
    const int* __restrict__ ssrc, const float* __restrict__ sea,
    const float* __restrict__ w, const float* __restrict__ b, float* __restrict__ agg)
{
    const int tid  = threadIdx.x;
    const int lane = tid & 63;
    const unsigned foff = (unsigned)lane * 4;    // byte offset of packed feature pair (bf16)
    const int node = blockIdx.x * 4 + (tid >> 6);
    vf2 wr[EF];
    #pragma unroll
    for (int k = 0; k < EF; ++k) wr[k] = *(const vf2*)&w[k * HD + lane * 2];
    const vf2 bias = *(const vf2*)&b[lane * 2];
    const int beg = __builtin_amdgcn_readfirstlane(rs[node]);
    const int end = __builtin_amdgcn_readfirstlane(rs[node + 1]);
    vf2 acc = {0.0f, 0.0f};
    int e = beg;
    #define LDH(s) (*(const unsigned*)((const char*)h16 + (((unsigned)(s) << 8) + foff)))
    if (e + 4 <= end) {
        // prologue: load quad 0
        int s0 = ssrc[e], s1 = ssrc[e + 1], s2 = ssrc[e + 2], s3 = ssrc[e + 3];
        unsigned d0 = LDH(s0), d1 = LDH(s1), d2 = LDH(s2), d3 = LDH(s3);
        for (; e + 8 <= end; e += 4) {
            // issue next quad's index + h loads (always in-bounds: e+7 <= end-1)
            const int t0 = ssrc[e + 4], t1 = ssrc[e + 5], t2 = ssrc[e + 6], t3 = ssrc[e + 7];
            const unsigned g0 = LDH(t0), g1 = LDH(t1), g2 = LDH(t2), g3 = LDH(t3);
            // compute current quad; sea s_loads split in halves to cap live SGPRs
            const float* a0 = &sea[(size_t)e * EF];
            vf2 m0 = bias, m1 = bias, m2 = bias, m3 = bias;
            #pragma unroll
            for (int k = 0; k < EF; ++k) {
                m0 = fma2(splat2(a0[k]),      wr[k], m0);
                m1 = fma2(splat2(a0[16 + k]), wr[k], m1);
            }
            acc += max2(up2(d0) + m0, splat2(0.0f));
            acc += max2(up2(d1) + m1, splat2(0.0f));
            #pragma unroll
            for (int k = 0; k < EF; ++k) {
                m2 = fma2(splat2(a0[32 + k]), wr[k], m2);
                m3 = fma2(splat2(a0[48 + k]), wr[k], m3);
            }
            acc += max2(up2(d2) + m2, splat2(0.0f));
            acc += max2(up2(d3) + m3, splat2(0.0f));
            s0 = t0; s1 = t1; s2 = t2; s3 = t3;
            d0 = g0; d1 = g1; d2 = g2; d3 = g3;
        }
        // drain: compute the last preloaded quad
        {
            const float* a0 = &sea[(size_t)e * EF];
            vf2 m0 = bias, m1 = bias, m2 = bias, m3 = bias;
            #pragma unroll
            for (int k = 0; k < EF; ++k) {
                m0 = fma2(splat2(a0[k]),      wr[k], m0);
                m1 = fma2(splat2(a0[16 + k]), wr[k], m1);
            }
            acc += max2(up2(d0) + m0, splat2(0.0f));
            acc += max2(up2(d1) + m1, splat2(0.0f));
            #pragma unroll
            for (int k = 0; k < EF; ++k) {
                m2 = fma2(splat2(a0[32 + k]), wr[k], m2);
                m3 = fma2(splat2(a0[48 + k]), wr[k], m3);
            }
            acc += max2(up2(d2) + m2, splat2(0.0f));
            acc += max2(up2(d3) + m3, splat2(0.0f));
            e += 4;
        }
    }
    // remainder 0..3 edges
    for (; e < end; ++e) {
        const int sA = ssrc[e];
        const unsigned dA = LDH(sA);
        const float* aA = &sea[(size_t)e * EF];
        vf2 mA = bias;
        #pragma unroll
        for (int k = 0; k < EF; ++k) mA = fma2(splat2(aA[k]), wr[k], mA);
        acc += max2(up2(dA) + mA, splat2(0.0f));
    }
    #undef LDH
    *(vf2*)&agg[(size_t)node * HD + lane * 2] = acc;
}

// ---------------- MFMA node-GEMM building blocks ----------------
#define ROW128 272   // 128 bf16 = 256 B + 16 pad
#define ROW32  80    // 32 bf16 = 64 B + 16 pad

// layer consuming internal ACTIVATIONS (hi-only B): 2 MFMAs per (fb,kb).
// R9: double-buffered weight prefetch -- keeps 8 independent weight loads in
// flight under each MFMA cluster (was L2-latency serial before; -10 us total).
__device__ __forceinline__ void mfma_layer128_act(
    const unsigned char* __restrict__ aH,
    const u16* __restrict__ wH, const u16* __restrict__ wL,
    const float* __restrict__ bias, int lane, vf4* __restrict__ acc)
{
    const int quad = lane >> 4, fm = lane & 15;
    int4 Bh[4];
    #pragma unroll
    for (int kb = 0; kb < 4; ++kb)
        Bh[kb] = *(const int4*)(aH + fm * ROW128 + kb * 64 + quad * 16);
    int4 wh0[4], wl0[4], wh1[4], wl1[4];
    #pragma unroll
    for (int kb = 0; kb < 4; ++kb) {
        wh0[kb] = *(const int4*)(wH + ((0 * 4 + kb) * 64 + lane) * 8);
        wl0[kb] = *(const int4*)(wL + ((0 * 4 + kb) * 64 + lane) * 8);
    }
    #pragma unroll
    for (int fbp = 0; fbp < 4; ++fbp) {
        const int fbA = fbp * 2, fbB = fbp * 2 + 1;
        // issue fbB's loads before fbA's MFMAs
        #pragma unroll
        for (int kb = 0; kb < 4; ++kb) {
            wh1[kb] = *(const int4*)(wH + ((fbB * 4 + kb) * 64 + lane) * 8);
            wl1[kb] = *(const int4*)(wL + ((fbB * 4 + kb) * 64 + lane) * 8);
        }
        {
            const float4 bv = *(const float4*)&bias[fbA * 16 + quad * 4];
            vf4 a = {bv.x, bv.y, bv.z, bv.w};
            #pragma unroll
            for (int kb = 0; kb < 4; ++kb) {
                a = __builtin_amdgcn_mfma_f32_16x16x32_bf16(BC8(wl0[kb]), BC8(Bh[kb]), a, 0, 0, 0);
                a = __builtin_amdgcn_mfma_f32_16x16x32_bf16(BC8(wh0[kb]), BC8(Bh[kb]), a, 0, 0, 0);
            }
            acc[fbA] = a;
        }
        // issue next pair's fbA loads before fbB's MFMAs
        if (fbp < 3) {
            #pragma unroll
            for (int kb = 0; kb < 4; ++kb) {
                wh0[kb] = *(const int4*)(wH + (((fbA + 2) * 4 + kb) * 64 + lane) * 8);
                wl0[kb] = *(const int4*)(wL + (((fbA + 2) * 4 + kb) * 64 + lane) * 8);
            }
        }
        {
            const float4 bv = *(const float4*)&bias[fbB * 16 + quad * 4];
            vf4 a = {bv.x, bv.y, bv.z, bv.w};
            #pragma unroll
            for (int kb = 0; kb < 4; ++kb) {
                a = __builtin_amdgcn_mfma_f32_16x16x32_bf16(BC8(wl1[kb]), BC8(Bh[kb]), a, 0, 0, 0);
                a = __builtin_amdgcn_mfma_f32_16x16x32_bf16(BC8(wh1[kb]), BC8(Bh[kb]), a, 0, 0, 0);
            }
            acc[fbB] = a;
        }
    }
}

__device__ __forceinline__ void mfma_layer32_in(
    const unsigned char* __restrict__ aH, const unsigned char* __restrict__ aL,
    const u16* __restrict__ wH, const u16* __restrict__ wL,
    const float* __restrict__ bias, int lane, vf4* __restrict__ acc)
{
    const int quad = lane >> 4, fm = lane & 15;
    const int4 Bh = *(const int4*)(aH + fm * ROW32 + quad * 16);
    const int4 Bl = *(const int4*)(aL + fm * ROW32 + quad * 16);
    #pragma unroll
    for (int fb = 0; fb < 8; ++fb) {
        const float4 bv = *(const float4*)&bias[fb * 16 + quad * 4];
        vf4 a = {bv.x, bv.y, bv.z, bv.w};
        const int4 wh = *(const int4*)(wH + (fb * 64 + lane) * 8);
        const int4 wl = *(const int4*)(wL + (fb * 64 + lane) * 8);
        a = __builtin_amdgcn_mfma_f32_16x16x32_bf16(BC8(wh), BC8(Bl), a, 0, 0, 0);
        a = __builtin_amdgcn_mfma_f32_16x16x32_bf16(BC8(wl), BC8(Bh), a, 0, 0, 0);
        a = __builtin_amdgcn_mfma_f32_16x16x32_bf16(BC8(wh), BC8(Bh), a, 0, 0, 0);
        acc[fb] = a;
    }
}

// apply leaky, write hi-only activations to LDS (acc updated to post-activation values)
__device__ __forceinline__ void store_act_hi(
    unsigned char* __restrict__ aH, int lane, vf4* __restrict__ acc)
{
    const int quad = lane >> 4, fm = lane & 15;
    #pragma unroll
    for (int fb = 0; fb < 8; ++fb) {
        const float4 s = {leakyf(acc[fb][0]), leakyf(acc[fb][1]), leakyf(acc[fb][2]), leakyf(acc[fb][3])};
        acc[fb][0] = s.x; acc[fb][1] = s.y; acc[fb][2] = s.z; acc[fb][3] = s.w;
        *(uint2*)(aH + fm * ROW128 + fb * 32 + quad * 8) = cvt4hi(s);
    }
}

// ---------------- node MLP layer 1 (MFMA, wave-private slab, NO block barriers) ----------------
// Additionally writes the bf16 mirror of h (hb16) consumed by e2's gather.
__global__ __launch_bounds__(256) void n1_kernel(
    const float* __restrict__ x, const float* __restrict__ agg,
    const u16* __restrict__ w1h, const u16* __restrict__ w1l, const float* __restrict__ b1,
    const u16* __restrict__ w2h, const u16* __restrict__ w2l, const float* __restrict__ b2,
    float* __restrict__ hout, u16* __restrict__ hb16)
{
    __shared__ __align__(16) unsigned char smem[4][2560 + 16 * ROW128];
    const int tid = threadIdx.x, lane = tid & 63, wid = tid >> 6;
    const int quad = lane >> 4, fm = lane & 15;
    const int tile = blockIdx.x * 4 + wid;
    unsigned char* inH = smem[wid];
    unsigned char* inL = inH + 16 * ROW32;
    unsigned char* aH  = inH + 2560;
    const size_t base = (size_t)tile * 16 * NF;
    #pragma unroll
    for (int i = 0; i < 2; ++i) {
        const int flat = i * 64 + lane;
        const int node = flat >> 3, kq = flat & 7;
        const float4 xv = *(const float4*)&x[base + node * NF + kq * 4];
        const float4 av = *(const float4*)&agg[base + node * NF + kq * 4];
        const float4 s = {xv.x + av.x, xv.y + av.y, xv.z + av.z, xv.w + av.w};
        uint2 phi, plo;
        cvt4(s, phi, plo);
        *(uint2*)(inH + node * ROW32 + kq * 8) = phi;
        *(uint2*)(inL + node * ROW32 + kq * 8) = plo;
    }
    WB();
    vf4 acc[8];
    mfma_layer32_in(inH, inL, w1h, w1l, b1, lane, acc);
    WB();
    store_act_hi(aH, lane, acc);
    WB();
    mfma_layer128_act(aH, w2h, w2l, b2, lane, acc);
    const size_t ob = (size_t)tile * 16 * HD;
    #pragma unroll
    for (int fb = 0; fb < 8; ++fb) {
        const float4 o = {fmaxf(acc[fb][0], 0.0f), fmaxf(acc[fb][1], 0.0f),
                          fmaxf(acc[fb][2], 0.0f), fmaxf(acc[fb][3], 0.0f)};
        *(float4*)&hout[ob + fm * HD + fb * 16 + quad * 4] = o;
        // bf16 mirror: row (tile*16+fm), dword d holds features 2d | 2d+1<<16
        *(uint2*)((unsigned char*)hb16 + (((size_t)(tile * 16 + fm)) << 8) + fb * 32 + quad * 8)
            = cvt4hi(o);
    }
}

// ---- node layer 2 + pooling + node-score head (MFMA, wave-private slab, NO block barriers) ----
__global__ __launch_bounds__(256) void n2_kernel(
    const float* __restrict__ h, const float* __restrict__ agg,
    const u16* __restrict__ w1h, const u16* __restrict__ w1l, const float* __restrict__ b1,
    const u16* __restrict__ w2h, const u16* __restrict__ w2l, const float* __restrict__ b2,
    const u16* __restrict__ m1h, const u16* __restrict__ m1l, const float* __restrict__ nb1,
    const u16* __restrict__ m2h, const u16* __restrict__ m2l, const float* __restrict__ nb2,
    const float* __restrict__ nw3, const float* __restrict__ nb3,
    float* __restrict__ pooled, float* __restrict__ scores)
{
    __shared__ __align__(16) unsigned char smem[4][16 * ROW128];
    const int tid = threadIdx.x, lane = tid & 63, wid = tid >> 6;
    const int quad = lane >> 4, fm = lane & 15;
    const int tile = blockIdx.x * 4 + wid;
    unsigned char* aH = smem[wid];
    const size_t base = (size_t)tile * 16 * HD;
    #pragma unroll
    for (int i = 0; i < 8; ++i) {
        const int flat = i * 64 + lane;
        const int node = flat >> 5, kq = flat & 31;
        const float4 hv = *(const float4*)&h[base + node * HD + kq * 4];
        const float4 av = *(const float4*)&agg[base + node * HD + kq * 4];
        const float4 s = {hv.x + av.x, hv.y + av.y, hv.z + av.z, hv.w + av.w};
        *(uint2*)(aH + node * ROW128 + kq * 8) = cvt4hi(s);
    }
    WB();
    vf4 acc[8];
    mfma_layer128_act(aH, w1h, w1l, b1, lane, acc);       // hi-only input, hi+lo weights
    WB();
    store_act_hi(aH, lane, acc);
    WB();
    mfma_layer128_act(aH, w2h, w2l, b2, lane, acc);
    WB();
    store_act_hi(aH, lane, acc);                          // acc now holds h2 (leaky'd)
    {
        const int g = tile >> 6;
        #pragma unroll
        for (int fb = 0; fb < 8; ++fb) {
            vf4 t = acc[fb];
            #pragma unroll
            for (int off = 1; off < 16; off <<= 1) {
                t[0] += __shfl_xor(t[0], off, 64);
                t[1] += __shfl_xor(t[1], off, 64);
                t[2] += __shfl_xor(t[2], off, 64);
                t[3] += __shfl_xor(t[3], off, 64);
            }
            #pragma unroll
            for (int r = 0; r < 4; ++r) {
                const int item = fb * 4 + r;
                if (fm == (item >> 1))
                    atomicAdd(&pooled[g * HD + fb * 16 + quad * 4 + r], t[r]);
            }
        }
    }
    WB();
    mfma_layer128_act(aH, m1h, m1l, nb1, lane, acc);
    WB();
    store_act_hi(aH, lane, acc);
    WB();
    mfma_layer128_act(aH, m2h, m2l, nb2, lane, acc);
    float v = 0.0f;
    #pragma unroll
    for (int fb = 0; fb < 8; ++fb) {
        const float4 w3v = *(const float4*)&nw3[fb * 16 + quad * 4];
        v += leakyf(acc[fb][0]) * w3v.x + leakyf(acc[fb][1]) * w3v.y
           + leakyf(acc[fb][2]) * w3v.z + leakyf(acc[fb][3]) * w3v.w;
    }
    v += __shfl_xor(v, 16, 64);
    v += __shfl_xor(v, 32, 64);
    if (lane < 16) {
        const int node = tile * 16 + fm;
        const float s = v + nb3[0];
        scores[(node & 63) * NPER + (node >> 6)] = 1.0f / (1.0f + expf(-s));
    }
}

// ---------------- action head: pooled mean -> MLP -> softmax ----------------
__global__ __launch_bounds__(128) void act_kernel(
    const float* __restrict__ pooled,
    const float* __restrict__ w1, const float* __restrict__ b1,
    const float* __restrict__ w2, const float* __restrict__ b2,
    float* __restrict__ out)
{
    __shared__ __align__(16) float p[HD];
    __shared__ float a1[HD];
    __shared__ float z[NACT];
    __shared__ float red2[2];
    const int g = blockIdx.x;
    const int tid = threadIdx.x;
    p[tid] = pooled[g * HD + tid] * (1.0f / NPER);
    __syncthreads();
    float acc = b1[tid];
    for (int k = 0; k < HD; ++k) acc = fmaf(p[k], w1[k * HD + tid], acc);
    a1[tid] = leakyf(acc);
    __syncthreads();
    if (tid < NACT) {
        float a2 = b2[tid];
        for (int k = 0; k < HD; ++k) a2 = fmaf(a1[k], w2[k * NACT + tid], a2);
        z[tid] = leakyf(a2);
    }
    __syncthreads();
    if (tid == 0) {
        float m = z[0];
        for (int i = 1; i < NACT; ++i) m = fmaxf(m, z[i]);
        red2[0] = m;
    }
    __syncthreads();
    if (tid < NACT) z[tid] = expf(z[tid] - red2[0]);
    __syncthreads();
    if (tid == 0) {
        float s = 0.0f;
        for (int i = 0; i < NACT; ++i) s += z[i];
        red2[1] = s;
    }
    __syncthreads();
    if (tid < NACT) out[g * NACT + tid] = z[tid] / red2[1];
}

extern "C" void kernel_launch(void* const* d_in, const int* in_sizes, int n_in,
                              void* d_out, int out_size, void* d_ws, size_t ws_size,
                              hipStream_t stream)
{
    const float* x    = (const float*)d_in[0];
    const int*   ei   = (const int*)d_in[1];     // int32
    const float* ea   = (const float*)d_in[2];
    const float* e1w  = (const float*)d_in[3];
    const float* e1b  = (const float*)d_in[4];
    const float* c1w1 = (const float*)d_in[5];
    const float* c1b1 = (const float*)d_in[6];
    const float* c1w2 = (const float*)d_in[7];
    const float* c1b2 = (const float*)d_in[8];
    const float* e2w  = (const float*)d_in[9];
    const float* e2b  = (const float*)d_in[10];
    const float* c2w1 = (const float*)d_in[11];
    const float* c2b1 = (const float*)d_in[12];
    const float* c2w2 = (const float*)d_in[13];
    const float* c2b2 = (const float*)d_in[14];
    const float* aw1  = (const float*)d_in[15];
    const float* ab1  = (const float*)d_in[16];
    const float* aw2  = (const float*)d_in[17];
    const float* ab2  = (const float*)d_in[18];
    const float* nw1  = (const float*)d_in[19];
    const float* nb1  = (const float*)d_in[20];
    const float* nw2  = (const float*)d_in[21];
    const float* nb2  = (const float*)d_in[22];
    const float* nw3  = (const float*)d_in[23];
    const float* nb3  = (const float*)d_in[24];

    float* out = (float*)d_out;
    char*  ws  = (char*)d_ws;
    const size_t MB = 1024 * 1024;
    float* h      = (float*)(ws);
    float* agg2   = (float*)(ws + 32  * MB);
    int*   seidx  = (int*)  (ws + 32  * MB);     // dead before e2_agg writes agg2
    float* sea    = (float*)(ws + 64  * MB);
    float* agg1   = (float*)(ws + 128 * MB);
    float* pooled = (float*)(ws + 136 * MB);
    u16*   pw     = (u16*)  (ws + 136 * MB + 64 * 1024);
    int*   cnt    = (int*)  (ws + 137 * MB);
    int*   rank   = (int*)  (ws + 138 * MB);     // per-edge slot rank (4 MB)
    int*   rs     = (int*)  (ws + 142 * MB);
    int*   ssrc   = (int*)  (ws + 143 * MB);
    u16*   hb16   = (u16*)  (ws + 147 * MB);     // 16 MB bf16 mirror of h
    u16*   x16    = (u16*)  (ws + 163 * MB);     // 4 MB bf16 mirror of x

    u16* p_c1w1 = pw;
    u16* p_c1w2 = pw + 1 * 32768;
    u16* p_c2w1 = pw + 2 * 32768;
    u16* p_c2w2 = pw + 3 * 32768;
    u16* p_nw1  = pw + 4 * 32768;
    u16* p_nw2  = pw + 5 * 32768;

    hipMemsetAsync(cnt,    0, NNODES * sizeof(int), stream);
    hipMemsetAsync(pooled, 0, (size_t)NB * HD * sizeof(float), stream);

    pack_all_kernel<<<336, 256, 0, stream>>>(c1w1, c1w2, c2w1, c2w2, nw1, nw2, pw);
    cvtx_kernel<<<NNODES * NF / 4 / 256, 256, 0, stream>>>(x, x16);

    hist_kernel<<<NEDGES / 256, 256, 0, stream>>>(ei, cnt, rank);
    scan_kernel<<<1, 1024, 0, stream>>>(cnt, rs);
    scatter_kernel<<<NEDGES / 256, 256, 0, stream>>>(ei, rs, rank, ssrc, seidx);
    permute_kernel<<<NEDGES / 64, 256, 0, stream>>>(seidx, ea, sea);

    e1_agg_kernel<<<NNODES / 16, 256, 0, stream>>>(x16, rs, ssrc, sea, e1w, e1b, agg1);
    n1_kernel<<<NNODES / 64, 256, 0, stream>>>(x, agg1,
                                               p_c1w1, p_c1w1 + 16384, c1b1,
                                               p_c1w2, p_c1w2 + 16384, c1b2, h, hb16);
    e2_agg_kernel<<<NNODES / 4, 256, 0, stream>>>(hb16, rs, ssrc, sea, e2w, e2b, agg2);
    n2_kernel<<<NNODES / 64, 256, 0, stream>>>(h, agg2,
                                               p_c2w1, p_c2w1 + 16384, c2b1,
                                               p_c2w2, p_c2w2 + 16384, c2b2,
                                               p_nw1,  p_nw1  + 16384, nb1,
                                               p_nw2,  p_nw2  + 16384, nb2,
                                               nw3, nb3, pooled, out + NB * NACT);
    act_kernel<<<NB, 128, 0, stream>>>(pooled, aw1, ab1, aw2, ab2, out);
}